// Round 2
// baseline (4840.875 us; speedup 1.0000x reference)
//
#include <hip/hip_runtime.h>

typedef unsigned short ushort_t;
typedef unsigned int uint_t;
typedef __bf16 bf16_t;
typedef bf16_t bf16x8 __attribute__((ext_vector_type(8)));
typedef float floatx4 __attribute__((ext_vector_type(4)));

// ---- constants for this problem ----
#define BATCH 4
#define SEQ   2048
#define DMODEL 1024
#define NHEAD 16
#define DH    64
#define BHSD  (BATCH*NHEAD*SEQ*DH)   // 8388608 elements per q/k/v tensor

// ---- bf16 <-> f32 helpers ----
__device__ __forceinline__ float b2f(ushort_t u) {
    uint_t x = ((uint_t)u) << 16;
    return __uint_as_float(x);
}
__device__ __forceinline__ ushort_t f2b(float f) {
    uint_t u = __float_as_uint(f);
    u = (u + 0x7fffu + ((u >> 16) & 1u)) >> 16;   // RNE
    return (ushort_t)u;
}

// ============================================================
// Kernel C: f32 -> bf16 cast (vectorized x4)
// ============================================================
__global__ __launch_bounds__(256) void cast_kernel(
    const float* __restrict__ in, ushort_t* __restrict__ out, int n)
{
    int i = (blockIdx.x * 256 + threadIdx.x) * 4;
    if (i >= n) return;
    float4 v = *(const float4*)&in[i];
    ushort4 o;
    o.x = f2b(v.x); o.y = f2b(v.y); o.z = f2b(v.z); o.w = f2b(v.w);
    *(ushort4*)&out[i] = o;
}

// ============================================================
// Kernel 0: RoPE cos/sin table  [SEQ][32]
// ============================================================
__global__ void rope_table_kernel(const int* __restrict__ tp,
                                  float* __restrict__ ct,
                                  float* __restrict__ st) {
    int idx = blockIdx.x * 256 + threadIdx.x;   // 0 .. SEQ*32-1
    int s = idx >> 5;
    int i = idx & 31;
    float pos = (float)tp[s];
    float invf = expf(-(float)i * 0.28782313662425572f); // ln(10000)/32
    float ang = pos * invf;
    float sv, cv;
    sincosf(ang, &sv, &cv);
    ct[idx] = cv;
    st[idx] = sv;
}

// ============================================================
// MFMA gemm_bt core: C[128x128 tile] = A[M x K] * B[N x K]^T
// 256 threads = 4 waves, wave grid 2x2, each wave 64x64 via
// 4x4 grid of 16x16x32 bf16 MFMA. K multiple of 32 assumed.
// Verified mappings: A/B frag [row=lane&15][k=quad*8+j],
//                    C/D [row=quad*4+r][col=lane&15].
// ============================================================
__device__ __forceinline__ void gemm_bt_tile(
    const ushort_t* __restrict__ A, const ushort_t* __restrict__ B, int K,
    int mbase, int nbase, floatx4 acc[4][4],
    ushort_t* __restrict__ As, ushort_t* __restrict__ Bs)
{
    const int tid  = threadIdx.x;
    const int lane = tid & 63;
    const int wave = tid >> 6;
    const int wm   = (wave >> 1) << 6;
    const int wn   = (wave & 1) << 6;
    const int quad = lane >> 4;
    const int l16  = lane & 15;
    const int srow = tid >> 2;          // 0..63
    const int scol = (tid & 3) << 3;    // 0,8,16,24

#pragma unroll
    for (int mi = 0; mi < 4; mi++)
#pragma unroll
        for (int ni = 0; ni < 4; ni++)
            acc[mi][ni] = (floatx4){0.f, 0.f, 0.f, 0.f};

    for (int k0 = 0; k0 < K; k0 += 32) {
        __syncthreads();
        *(uint4*)&As[(srow     ) * 32 + scol] = *(const uint4*)&A[(size_t)(mbase + srow     ) * K + k0 + scol];
        *(uint4*)&As[(srow + 64) * 32 + scol] = *(const uint4*)&A[(size_t)(mbase + srow + 64) * K + k0 + scol];
        *(uint4*)&Bs[(srow     ) * 32 + scol] = *(const uint4*)&B[(size_t)(nbase + srow     ) * K + k0 + scol];
        *(uint4*)&Bs[(srow + 64) * 32 + scol] = *(const uint4*)&B[(size_t)(nbase + srow + 64) * K + k0 + scol];
        __syncthreads();

        bf16x8 af[4], bfr[4];
#pragma unroll
        for (int i = 0; i < 4; i++)
            af[i]  = *(const bf16x8*)&As[(wm + i * 16 + l16) * 32 + quad * 8];
#pragma unroll
        for (int i = 0; i < 4; i++)
            bfr[i] = *(const bf16x8*)&Bs[(wn + i * 16 + l16) * 32 + quad * 8];

#pragma unroll
        for (int mi = 0; mi < 4; mi++)
#pragma unroll
            for (int ni = 0; ni < 4; ni++)
                acc[mi][ni] = __builtin_amdgcn_mfma_f32_16x16x32_bf16(
                    af[mi], bfr[ni], acc[mi][ni], 0, 0, 0);
    }
}

// ============================================================
// Kernel 1: QKV projection + fused RoPE (q,k), scatter to
// [3][B][H][S][DH] bf16 workspace.
// grid (M/128=64, N/128=8, 3), block 256
// ============================================================
__global__ __launch_bounds__(256) void qkv_rope_kernel(
    const ushort_t* __restrict__ x, const ushort_t* __restrict__ Wqkv,
    const float* __restrict__ ctab, const float* __restrict__ stab,
    ushort_t* __restrict__ qkv)
{
    __shared__ __align__(16) ushort_t As[128 * 32];
    __shared__ __align__(16) ushort_t Bs[128 * 32];
    floatx4 acc[4][4];

    const int which = blockIdx.z;
    const int mbase = blockIdx.x * 128;
    const int nbase = blockIdx.y * 128;

    gemm_bt_tile(x, Wqkv + (size_t)which * DMODEL * DMODEL, DMODEL,
                 mbase, nbase, acc, As, Bs);

    const int lane = threadIdx.x & 63;
    const int wave = threadIdx.x >> 6;
    const int wm = (wave >> 1) << 6, wn = (wave & 1) << 6;
    const int quad = lane >> 4, l16 = lane & 15;

#pragma unroll
    for (int mi = 0; mi < 4; mi++) {
#pragma unroll
        for (int ni = 0; ni < 4; ni++) {
#pragma unroll
            for (int r = 0; r < 4; r++) {
                int grow = mbase + wm + mi * 16 + quad * 4 + r;   // b*S + s
                int gcol = nbase + wn + ni * 16 + l16;            // h*64 + dd
                float val = acc[mi][ni][r];
                float partner = __shfl_xor(val, 1);
                int s  = grow & (SEQ - 1);
                int dd = gcol & (DH - 1);
                float res = val;
                if (which < 2) {
                    int fi = dd >> 1;
                    float cs = ctab[s * 32 + fi];
                    float sn = stab[s * 32 + fi];
                    // even col: x1*c - x2*s ; odd col: x1*s + x2*c
                    res = (gcol & 1) ? fmaf(partner, sn, val * cs)
                                     : fmaf(val, cs, -partner * sn);
                }
                int b = grow >> 11;        // / SEQ
                int h = gcol >> 6;         // / DH
                size_t dst = ((size_t)which * (BATCH * NHEAD) + b * NHEAD + h)
                                 * ((size_t)SEQ * DH)
                             + (size_t)s * DH + dd;
                qkv[dst] = f2b(res);
            }
        }
    }
}

// ============================================================
// Kernel 2: scalar flash attention (correctness baseline).
// block = 256 = 4 waves, wave w handles query row q0+w of one
// (b,h). Online softmax over causal 64-key chunks staged in LDS.
// grid (S/4=512, B*H=64)
// ============================================================
__global__ __launch_bounds__(256) void attn_flash_kernel(
    const ushort_t* __restrict__ qT, const ushort_t* __restrict__ kT,
    const ushort_t* __restrict__ vT, ushort_t* __restrict__ attnout)
{
    __shared__ float kt[64 * 65];   // transposed [d][j], padded
    __shared__ float vt[64 * 64];   // [j][d]

    const int tid = threadIdx.x;
    const int wave = tid >> 6;
    const int lane = tid & 63;
    const int bh = blockIdx.y;
    const int b = bh >> 4, h = bh & 15;
    const int q0 = blockIdx.x * 4;
    const int qrow = q0 + wave;
    const size_t base = (size_t)bh * SEQ * DH;

    float qreg = b2f(qT[base + (size_t)qrow * DH + lane]);
    float m = -INFINITY, l = 0.f, acc = 0.f;   // acc: O[d=lane]

    const int nc = (q0 + 3) / 64 + 1;
    for (int c = 0; c < nc; ++c) {
        __syncthreads();
#pragma unroll
        for (int r = 0; r < 16; ++r) {
            int idx = r * 256 + tid;
            int jj = idx >> 6, d = idx & 63;
            size_t g = base + (size_t)(c * 64 + jj) * DH + d;
            kt[d * 65 + jj] = b2f(kT[g]);
            vt[jj * 64 + d] = b2f(vT[g]);
        }
        __syncthreads();

        if (c * 64 <= qrow) {
            // scores: this lane = key j within chunk
            float s = 0.f;
#pragma unroll
            for (int d = 0; d < 64; ++d)
                s = fmaf(__shfl(qreg, d), kt[d * 65 + lane], s);
            s *= 0.125f;   // 1/sqrt(64)
            int jg = c * 64 + lane;
            if (jg > qrow) s = -INFINITY;

            float cm = s;
#pragma unroll
            for (int off = 32; off > 0; off >>= 1)
                cm = fmaxf(cm, __shfl_xor(cm, off));
            float mn = fmaxf(m, cm);
            float p = __expf(s - mn);          // masked -> 0
            float alpha = __expf(m - mn);      // first chunk: exp(-inf)=0
            float ps = p;
#pragma unroll
            for (int off = 32; off > 0; off >>= 1)
                ps += __shfl_xor(ps, off);
            l = l * alpha + ps;
            acc *= alpha;
#pragma unroll
            for (int j = 0; j < 64; ++j)
                acc = fmaf(__shfl(p, j), vt[j * 64 + lane], acc);
            m = mn;
        }
    }

    float out = acc / l;
    // write [b][s=qrow][h*64 + lane]
    attnout[((size_t)(b * SEQ + qrow)) * DMODEL + h * DH + lane] = f2b(out);
}

// ============================================================
// Kernel 3: output projection  out = attn @ W_o^T  (f32 out)
// grid (64, 8), block 256
// ============================================================
__global__ __launch_bounds__(256) void outproj_kernel(
    const ushort_t* __restrict__ Ain, const ushort_t* __restrict__ Wo,
    float* __restrict__ out)
{
    __shared__ __align__(16) ushort_t As[128 * 32];
    __shared__ __align__(16) ushort_t Bs[128 * 32];
    floatx4 acc[4][4];

    const int mbase = blockIdx.x * 128;
    const int nbase = blockIdx.y * 128;
    gemm_bt_tile(Ain, Wo, DMODEL, mbase, nbase, acc, As, Bs);

    const int lane = threadIdx.x & 63;
    const int wave = threadIdx.x >> 6;
    const int wm = (wave >> 1) << 6, wn = (wave & 1) << 6;
    const int quad = lane >> 4, l16 = lane & 15;

#pragma unroll
    for (int mi = 0; mi < 4; mi++)
#pragma unroll
        for (int ni = 0; ni < 4; ni++)
#pragma unroll
            for (int r = 0; r < 4; r++) {
                int grow = mbase + wm + mi * 16 + quad * 4 + r;
                int gcol = nbase + wn + ni * 16 + l16;
                out[(size_t)grow * DMODEL + gcol] = acc[mi][ni][r];
            }
}

// ============================================================
// launcher
// ============================================================
extern "C" void kernel_launch(void* const* d_in, const int* in_sizes, int n_in,
                              void* d_out, int out_size, void* d_ws, size_t ws_size,
                              hipStream_t stream) {
    const float* x_f    = (const float*)d_in[0];   // [B,S,D] f32
    const float* Wqkv_f = (const float*)d_in[1];   // [3,D,D] f32
    const float* Wo_f   = (const float*)d_in[2];   // [D,D] f32
    const int* tp       = (const int*)d_in[3];     // [S] i32
    float* out          = (float*)d_out;           // [B,S,D] f32

    char* ws = (char*)d_ws;
    // workspace layout (bytes):
    //   qkv bf16 [3][B][H][S][DH] : 0              .. 50331648
    //   attnout bf16 [B][S][D]    : 50331648       .. 67108864
    //   cos table f32 [S][32]     : 67108864       .. 67371008
    //   sin table f32 [S][32]     : 67371008       .. 67633152
    //   xb bf16 [B*S*D]           : 67633152       .. 84410368
    //   Wqkvb bf16 [3*D*D]        : 84410368       .. 90701824
    //   Wob bf16 [D*D]            : 90701824       .. 92798976
    ushort_t* qkv     = (ushort_t*)(ws);
    ushort_t* attnout = (ushort_t*)(ws + 50331648);
    float* ctab       = (float*)(ws + 67108864);
    float* stab       = (float*)(ws + 67371008);
    ushort_t* xb      = (ushort_t*)(ws + 67633152);
    ushort_t* Wqkvb   = (ushort_t*)(ws + 84410368);
    ushort_t* Wob     = (ushort_t*)(ws + 90701824);

    const int n_x  = BATCH * SEQ * DMODEL;      // 8388608
    const int n_wq = 3 * DMODEL * DMODEL;       // 3145728
    const int n_wo = DMODEL * DMODEL;           // 1048576

    cast_kernel<<<dim3(n_x  / 1024), dim3(256), 0, stream>>>(x_f,    xb,    n_x);
    cast_kernel<<<dim3(n_wq / 1024), dim3(256), 0, stream>>>(Wqkv_f, Wqkvb, n_wq);
    cast_kernel<<<dim3(n_wo / 1024), dim3(256), 0, stream>>>(Wo_f,   Wob,   n_wo);

    rope_table_kernel<<<dim3(SEQ * 32 / 256), dim3(256), 0, stream>>>(tp, ctab, stab);

    qkv_rope_kernel<<<dim3(BATCH * SEQ / 128, DMODEL / 128, 3), dim3(256), 0, stream>>>(
        xb, Wqkvb, ctab, stab, qkv);

    attn_flash_kernel<<<dim3(SEQ / 4, BATCH * NHEAD), dim3(256), 0, stream>>>(
        qkv, qkv + BHSD, qkv + 2 * (size_t)BHSD, attnout);

    outproj_kernel<<<dim3(BATCH * SEQ / 128, DMODEL / 128), dim3(256), 0, stream>>>(
        attnout, Wob, out);
}

// Round 3
// 470.944 us; speedup vs baseline: 10.2791x; 10.2791x over previous
//
#include <hip/hip_runtime.h>

typedef unsigned short ushort_t;
typedef unsigned int uint_t;
typedef __bf16 bf16_t;
typedef bf16_t bf16x8 __attribute__((ext_vector_type(8)));
typedef float floatx4 __attribute__((ext_vector_type(4)));

// ---- constants ----
#define BATCH 4
#define SEQ   2048
#define DMODEL 1024
#define NHEAD 16
#define DH    64
#define BHSD  (BATCH*NHEAD*SEQ*DH)   // 8388608 elements per q/k/v tensor

__device__ __forceinline__ float b2f(ushort_t u) {
    uint_t x = ((uint_t)u) << 16;
    return __uint_as_float(x);
}
__device__ __forceinline__ ushort_t f2b(float f) {
    uint_t u = __float_as_uint(f);
    u = (u + 0x7fffu + ((u >> 16) & 1u)) >> 16;   // RNE
    return (ushort_t)u;
}

// ============================================================
// f32 -> bf16 cast (x4 vectorized)
// ============================================================
__global__ __launch_bounds__(256) void cast_kernel(
    const float* __restrict__ in, ushort_t* __restrict__ out, int n)
{
    int i = (blockIdx.x * 256 + threadIdx.x) * 4;
    if (i >= n) return;
    float4 v = *(const float4*)&in[i];
    ushort4 o;
    o.x = f2b(v.x); o.y = f2b(v.y); o.z = f2b(v.z); o.w = f2b(v.w);
    *(ushort4*)&out[i] = o;
}

// ============================================================
// RoPE cos/sin table [SEQ][32]
// ============================================================
__global__ void rope_table_kernel(const int* __restrict__ tp,
                                  float* __restrict__ ct,
                                  float* __restrict__ st) {
    int idx = blockIdx.x * 256 + threadIdx.x;
    int s = idx >> 5;
    int i = idx & 31;
    float pos = (float)tp[s];
    float invf = expf(-(float)i * 0.28782313662425572f); // ln(10000)/32
    float ang = pos * invf;
    float sv, cv;
    sincosf(ang, &sv, &cv);
    ct[idx] = cv;
    st[idx] = sv;
}

// ============================================================
// MFMA gemm_bt core: C[128x128] = A[MxK] * B[NxK]^T
// Verified mappings: A/B frag [row=lane&15][k=quad*8+j],
//                    C/D [row=quad*4+r][col=lane&15].
// ============================================================
__device__ __forceinline__ void gemm_bt_tile(
    const ushort_t* __restrict__ A, const ushort_t* __restrict__ B, int K,
    int mbase, int nbase, floatx4 acc[4][4],
    ushort_t* __restrict__ As, ushort_t* __restrict__ Bs)
{
    const int tid  = threadIdx.x;
    const int lane = tid & 63;
    const int wave = tid >> 6;
    const int wm   = (wave >> 1) << 6;
    const int wn   = (wave & 1) << 6;
    const int quad = lane >> 4;
    const int l16  = lane & 15;
    const int srow = tid >> 2;
    const int scol = (tid & 3) << 3;

#pragma unroll
    for (int mi = 0; mi < 4; mi++)
#pragma unroll
        for (int ni = 0; ni < 4; ni++)
            acc[mi][ni] = (floatx4){0.f, 0.f, 0.f, 0.f};

    for (int k0 = 0; k0 < K; k0 += 32) {
        __syncthreads();
        *(uint4*)&As[(srow     ) * 32 + scol] = *(const uint4*)&A[(size_t)(mbase + srow     ) * K + k0 + scol];
        *(uint4*)&As[(srow + 64) * 32 + scol] = *(const uint4*)&A[(size_t)(mbase + srow + 64) * K + k0 + scol];
        *(uint4*)&Bs[(srow     ) * 32 + scol] = *(const uint4*)&B[(size_t)(nbase + srow     ) * K + k0 + scol];
        *(uint4*)&Bs[(srow + 64) * 32 + scol] = *(const uint4*)&B[(size_t)(nbase + srow + 64) * K + k0 + scol];
        __syncthreads();

        bf16x8 af[4], bfr[4];
#pragma unroll
        for (int i = 0; i < 4; i++)
            af[i]  = *(const bf16x8*)&As[(wm + i * 16 + l16) * 32 + quad * 8];
#pragma unroll
        for (int i = 0; i < 4; i++)
            bfr[i] = *(const bf16x8*)&Bs[(wn + i * 16 + l16) * 32 + quad * 8];

#pragma unroll
        for (int mi = 0; mi < 4; mi++)
#pragma unroll
            for (int ni = 0; ni < 4; ni++)
                acc[mi][ni] = __builtin_amdgcn_mfma_f32_16x16x32_bf16(
                    af[mi], bfr[ni], acc[mi][ni], 0, 0, 0);
    }
}

// ============================================================
// QKV projection + fused RoPE, scatter to [3][B][H][S][DH] bf16
// ============================================================
__global__ __launch_bounds__(256) void qkv_rope_kernel(
    const ushort_t* __restrict__ x, const ushort_t* __restrict__ Wqkv,
    const float* __restrict__ ctab, const float* __restrict__ stab,
    ushort_t* __restrict__ qkv)
{
    __shared__ __align__(16) ushort_t As[128 * 32];
    __shared__ __align__(16) ushort_t Bs[128 * 32];
    floatx4 acc[4][4];

    const int which = blockIdx.z;
    const int mbase = blockIdx.x * 128;
    const int nbase = blockIdx.y * 128;

    gemm_bt_tile(x, Wqkv + (size_t)which * DMODEL * DMODEL, DMODEL,
                 mbase, nbase, acc, As, Bs);

    const int lane = threadIdx.x & 63;
    const int wave = threadIdx.x >> 6;
    const int wm = (wave >> 1) << 6, wn = (wave & 1) << 6;
    const int quad = lane >> 4, l16 = lane & 15;

#pragma unroll
    for (int mi = 0; mi < 4; mi++) {
#pragma unroll
        for (int ni = 0; ni < 4; ni++) {
#pragma unroll
            for (int r = 0; r < 4; r++) {
                int grow = mbase + wm + mi * 16 + quad * 4 + r;   // b*S + s
                int gcol = nbase + wn + ni * 16 + l16;            // h*64 + dd
                float val = acc[mi][ni][r];
                float partner = __shfl_xor(val, 1);
                int s  = grow & (SEQ - 1);
                int dd = gcol & (DH - 1);
                float res = val;
                if (which < 2) {
                    int fi = dd >> 1;
                    float cs = ctab[s * 32 + fi];
                    float sn = stab[s * 32 + fi];
                    res = (gcol & 1) ? fmaf(partner, sn, val * cs)
                                     : fmaf(val, cs, -partner * sn);
                }
                int b = grow >> 11;
                int h = gcol >> 6;
                size_t dst = ((size_t)which * (BATCH * NHEAD) + b * NHEAD + h)
                                 * ((size_t)SEQ * DH)
                             + (size_t)s * DH + dd;
                qkv[dst] = f2b(res);
            }
        }
    }
}

// ============================================================
// V transpose: v[bh][s][dh] -> vt[bh][dh][s]
// grid (SEQ/64, B*H), block 256
// ============================================================
__global__ __launch_bounds__(256) void vtrans_kernel(
    const ushort_t* __restrict__ v, ushort_t* __restrict__ vt)
{
    __shared__ __align__(16) ushort_t t[64 * 72];
    const int tid = threadIdx.x;
    const int bh = blockIdx.y;
    const int s0 = blockIdx.x * 64;
    const size_t base = (size_t)bh * SEQ * DH;
    const int row = tid >> 2;            // 0..63
    const int c0  = (tid & 3) * 16;      // 0,16,32,48

    const ushort_t* g = &v[base + (size_t)(s0 + row) * DH + c0];
    *(uint4*)&t[row * 72 + c0]     = *(const uint4*)g;
    *(uint4*)&t[row * 72 + c0 + 8] = *(const uint4*)(g + 8);
    __syncthreads();

    ushort_t tmp[16];
#pragma unroll
    for (int j = 0; j < 16; ++j)
        tmp[j] = t[(c0 + j) * 72 + row];
    ushort_t* og = &vt[base + (size_t)row * SEQ + s0 + c0];
    *(uint4*)&og[0] = *(uint4*)&tmp[0];
    *(uint4*)&og[8] = *(uint4*)&tmp[8];
}

// ============================================================
// MFMA flash attention. Block = 256 thr = 4 waves, Q-tile 128
// rows per (b,h); wave w owns rows [w*32, w*32+32). K-tiles of
// 64 keys staged in LDS (stride 72 = conflict-free-ish).
// P round-trips through wave-private LDS (C-layout -> A-frags).
// grid (SEQ/128, B*H)
// ============================================================
__global__ __launch_bounds__(256) void attn_mfma_kernel(
    const ushort_t* __restrict__ q, const ushort_t* __restrict__ k,
    const ushort_t* __restrict__ vt, ushort_t* __restrict__ attnout)
{
    __shared__ __align__(16) ushort_t Ks[64 * 72];
    __shared__ __align__(16) ushort_t Vs[64 * 72];
    __shared__ __align__(16) ushort_t Ps[128 * 72];

    const int tid  = threadIdx.x;
    const int wave = tid >> 6;
    const int lane = tid & 63;
    const int quad = lane >> 4;
    const int l16  = lane & 15;
    const int bh = blockIdx.y;
    const int b = bh >> 4, h = bh & 15;
    const int q0 = blockIdx.x * 128;
    const size_t base = (size_t)bh * SEQ * DH;

    // Q fragments (A-layout) straight from global
    bf16x8 qf[2][2];
#pragma unroll
    for (int mi = 0; mi < 2; mi++)
#pragma unroll
        for (int kc = 0; kc < 2; kc++)
            qf[mi][kc] = *(const bf16x8*)&q[base
                + (size_t)(q0 + wave * 32 + mi * 16 + l16) * DH + kc * 32 + quad * 8];

    floatx4 o[2][4];
    float m_run[2][4], l_run[2][4];
#pragma unroll
    for (int mi = 0; mi < 2; mi++)
#pragma unroll
        for (int nd = 0; nd < 4; nd++)
            o[mi][nd] = (floatx4){0.f, 0.f, 0.f, 0.f};
#pragma unroll
    for (int mi = 0; mi < 2; mi++)
#pragma unroll
        for (int r = 0; r < 4; r++) {
            m_run[mi][r] = -INFINITY;
            l_run[mi][r] = 0.f;
        }

    const int srow = tid >> 2;          // 0..63
    const int sc0  = (tid & 3) * 16;

    const int ktmax = (q0 + 127) >> 6;
    for (int kt = 0; kt <= ktmax; ++kt) {
        __syncthreads();
        {
            const ushort_t* kg = &k[base + (size_t)(kt * 64 + srow) * DH + sc0];
            *(uint4*)&Ks[srow * 72 + sc0]     = *(const uint4*)kg;
            *(uint4*)&Ks[srow * 72 + sc0 + 8] = *(const uint4*)(kg + 8);
            const ushort_t* vg = &vt[base + (size_t)srow * SEQ + kt * 64 + sc0];
            *(uint4*)&Vs[srow * 72 + sc0]     = *(const uint4*)vg;
            *(uint4*)&Vs[srow * 72 + sc0 + 8] = *(const uint4*)(vg + 8);
        }
        __syncthreads();

        if (kt * 64 <= q0 + wave * 32 + 31) {   // wave-level causal skip
            // ---- QK^T ----
            floatx4 s[2][4];
#pragma unroll
            for (int mi = 0; mi < 2; mi++)
#pragma unroll
                for (int ni = 0; ni < 4; ni++)
                    s[mi][ni] = (floatx4){0.f, 0.f, 0.f, 0.f};
#pragma unroll
            for (int kc = 0; kc < 2; kc++) {
                bf16x8 kf[4];
#pragma unroll
                for (int ni = 0; ni < 4; ni++)
                    kf[ni] = *(const bf16x8*)&Ks[(ni * 16 + l16) * 72 + kc * 32 + quad * 8];
#pragma unroll
                for (int mi = 0; mi < 2; mi++)
#pragma unroll
                    for (int ni = 0; ni < 4; ni++)
                        s[mi][ni] = __builtin_amdgcn_mfma_f32_16x16x32_bf16(
                            qf[mi][kc], kf[ni], s[mi][ni], 0, 0, 0);
            }

            // ---- online softmax (per q-row = (mi, quad*4+r)) ----
#pragma unroll
            for (int mi = 0; mi < 2; mi++) {
#pragma unroll
                for (int r = 0; r < 4; r++) {
                    int row_g = q0 + wave * 32 + mi * 16 + quad * 4 + r;
                    float rm = -INFINITY;
#pragma unroll
                    for (int ni = 0; ni < 4; ni++) {
                        float v = s[mi][ni][r] * 0.125f;   // 1/sqrt(64)
                        int col_g = kt * 64 + ni * 16 + l16;
                        v = (col_g <= row_g) ? v : -INFINITY;
                        s[mi][ni][r] = v;
                        rm = fmaxf(rm, v);
                    }
                    rm = fmaxf(rm, __shfl_xor(rm, 1));
                    rm = fmaxf(rm, __shfl_xor(rm, 2));
                    rm = fmaxf(rm, __shfl_xor(rm, 4));
                    rm = fmaxf(rm, __shfl_xor(rm, 8));
                    float mo = m_run[mi][r];
                    float mn = fmaxf(mo, rm);
                    float alpha = __expf(mo - mn);   // first tile: exp(-inf)=0
                    float rs = 0.f;
#pragma unroll
                    for (int ni = 0; ni < 4; ni++) {
                        float p = __expf(s[mi][ni][r] - mn);
                        s[mi][ni][r] = p;
                        rs += p;
                    }
                    rs += __shfl_xor(rs, 1);
                    rs += __shfl_xor(rs, 2);
                    rs += __shfl_xor(rs, 4);
                    rs += __shfl_xor(rs, 8);
                    m_run[mi][r] = mn;
                    l_run[mi][r] = l_run[mi][r] * alpha + rs;
#pragma unroll
                    for (int nd = 0; nd < 4; nd++)
                        o[mi][nd][r] *= alpha;
                }
            }

            // ---- P: C-layout regs -> wave-private LDS (bf16) ----
#pragma unroll
            for (int mi = 0; mi < 2; mi++)
#pragma unroll
                for (int ni = 0; ni < 4; ni++)
#pragma unroll
                    for (int r = 0; r < 4; r++)
                        Ps[(wave * 32 + mi * 16 + quad * 4 + r) * 72 + ni * 16 + l16]
                            = f2b(s[mi][ni][r]);

            // ---- PV ----
#pragma unroll
            for (int kc = 0; kc < 2; kc++) {
                bf16x8 pf[2], vf[4];
#pragma unroll
                for (int mi = 0; mi < 2; mi++)
                    pf[mi] = *(const bf16x8*)&Ps[(wave * 32 + mi * 16 + l16) * 72 + kc * 32 + quad * 8];
#pragma unroll
                for (int nd = 0; nd < 4; nd++)
                    vf[nd] = *(const bf16x8*)&Vs[(nd * 16 + l16) * 72 + kc * 32 + quad * 8];
#pragma unroll
                for (int mi = 0; mi < 2; mi++)
#pragma unroll
                    for (int nd = 0; nd < 4; nd++)
                        o[mi][nd] = __builtin_amdgcn_mfma_f32_16x16x32_bf16(
                            pf[mi], vf[nd], o[mi][nd], 0, 0, 0);
            }
        }
    }

    // ---- epilogue: O / l, write [b][s][h*64+dh] bf16 ----
#pragma unroll
    for (int mi = 0; mi < 2; mi++)
#pragma unroll
        for (int nd = 0; nd < 4; nd++)
#pragma unroll
            for (int r = 0; r < 4; r++) {
                int s_idx = q0 + wave * 32 + mi * 16 + quad * 4 + r;
                float val = o[mi][nd][r] / l_run[mi][r];
                attnout[((size_t)(b * SEQ + s_idx)) * DMODEL + h * DH + nd * 16 + l16]
                    = f2b(val);
            }
}

// ============================================================
// output projection  out = attn @ W_o^T  (f32 out)
// ============================================================
__global__ __launch_bounds__(256) void outproj_kernel(
    const ushort_t* __restrict__ Ain, const ushort_t* __restrict__ Wo,
    float* __restrict__ out)
{
    __shared__ __align__(16) ushort_t As[128 * 32];
    __shared__ __align__(16) ushort_t Bs[128 * 32];
    floatx4 acc[4][4];

    const int mbase = blockIdx.x * 128;
    const int nbase = blockIdx.y * 128;
    gemm_bt_tile(Ain, Wo, DMODEL, mbase, nbase, acc, As, Bs);

    const int lane = threadIdx.x & 63;
    const int wave = threadIdx.x >> 6;
    const int wm = (wave >> 1) << 6, wn = (wave & 1) << 6;
    const int quad = lane >> 4, l16 = lane & 15;

#pragma unroll
    for (int mi = 0; mi < 4; mi++)
#pragma unroll
        for (int ni = 0; ni < 4; ni++)
#pragma unroll
            for (int r = 0; r < 4; r++) {
                int grow = mbase + wm + mi * 16 + quad * 4 + r;
                int gcol = nbase + wn + ni * 16 + l16;
                out[(size_t)grow * DMODEL + gcol] = acc[mi][ni][r];
            }
}

// ============================================================
// launcher
// ============================================================
extern "C" void kernel_launch(void* const* d_in, const int* in_sizes, int n_in,
                              void* d_out, int out_size, void* d_ws, size_t ws_size,
                              hipStream_t stream) {
    const float* x_f    = (const float*)d_in[0];
    const float* Wqkv_f = (const float*)d_in[1];
    const float* Wo_f   = (const float*)d_in[2];
    const int* tp       = (const int*)d_in[3];
    float* out          = (float*)d_out;

    char* ws = (char*)d_ws;
    // workspace layout (bytes):
    //   qkv bf16 [3][B][H][S][DH] : 0        .. 50331648
    //   attnout bf16 [B][S][D]    : 50331648 .. 67108864
    //   cos table f32 [S][32]     : 67108864 .. 67371008
    //   sin table f32 [S][32]     : 67371008 .. 67633152
    //   xb bf16 / vt bf16 (alias) : 67633152 .. 84410368
    //     (xb dead after qkv_rope; vt = transposed V reuses it)
    //   Wqkvb bf16 [3*D*D]        : 84410368 .. 90701824
    //   Wob bf16 [D*D]            : 90701824 .. 92798976
    ushort_t* qkv     = (ushort_t*)(ws);
    ushort_t* attnout = (ushort_t*)(ws + 50331648);
    float* ctab       = (float*)(ws + 67108864);
    float* stab       = (float*)(ws + 67371008);
    ushort_t* xb      = (ushort_t*)(ws + 67633152);
    ushort_t* vt      = (ushort_t*)(ws + 67633152);   // alias of xb
    ushort_t* Wqkvb   = (ushort_t*)(ws + 84410368);
    ushort_t* Wob     = (ushort_t*)(ws + 90701824);

    const int n_x  = BATCH * SEQ * DMODEL;
    const int n_wq = 3 * DMODEL * DMODEL;
    const int n_wo = DMODEL * DMODEL;

    cast_kernel<<<dim3(n_x  / 1024), dim3(256), 0, stream>>>(x_f,    xb,    n_x);
    cast_kernel<<<dim3(n_wq / 1024), dim3(256), 0, stream>>>(Wqkv_f, Wqkvb, n_wq);
    cast_kernel<<<dim3(n_wo / 1024), dim3(256), 0, stream>>>(Wo_f,   Wob,   n_wo);

    rope_table_kernel<<<dim3(SEQ * 32 / 256), dim3(256), 0, stream>>>(tp, ctab, stab);

    qkv_rope_kernel<<<dim3(BATCH * SEQ / 128, DMODEL / 128, 3), dim3(256), 0, stream>>>(
        xb, Wqkvb, ctab, stab, qkv);

    // transpose V (reads qkv v-section, writes vt over dead xb)
    vtrans_kernel<<<dim3(SEQ / 64, BATCH * NHEAD), dim3(256), 0, stream>>>(
        qkv + 2 * (size_t)BHSD, vt);

    attn_mfma_kernel<<<dim3(SEQ / 128, BATCH * NHEAD), dim3(256), 0, stream>>>(
        qkv, qkv + BHSD, vt, attnout);

    outproj_kernel<<<dim3(BATCH * SEQ / 128, DMODEL / 128), dim3(256), 0, stream>>>(
        attnout, Wob, out);
}